// Round 17
// baseline (345.228 us; speedup 1.0000x reference)
//
#include <hip/hip_runtime.h>
#include <hip/hip_bf16.h>

#define D 768
#define H 8
#define HD 96
#define MLP 3072
#define NB 2048
#define BATCH 4

typedef __attribute__((ext_vector_type(8))) short short8;
typedef __attribute__((ext_vector_type(4))) short short4v;
typedef __attribute__((ext_vector_type(4))) float f32x4;
typedef __attribute__((ext_vector_type(16))) float f32x16;
typedef __attribute__((ext_vector_type(4))) int int4v;

typedef const __attribute__((address_space(1))) unsigned int gu32;
typedef __attribute__((address_space(3))) unsigned int lu32;

__device__ inline void gload16(const void* g, void* l){
  __builtin_amdgcn_global_load_lds((gu32*)g, (lu32*)l, 16, 0, 0);
}

__device__ inline short f2b(float f){
  __hip_bfloat16 h = __float2bfloat16(f);
  return *reinterpret_cast<short*>(&h);
}
__device__ inline float b2f(short s){
  return __uint_as_float(((unsigned)(unsigned short)s) << 16);
}
__device__ inline float fexp2(float x){ return __builtin_amdgcn_exp2f(x); }

__device__ inline unsigned cvtpk(float lo, float hi){
  unsigned r;
  asm volatile("v_cvt_pk_bf16_f32 %0, %1, %2" : "=v"(r) : "v"(lo), "v"(hi));
  return r;
}

#define QSCALE 0.14724747f   // (1/sqrt(96)) * log2(e), folded into Q projection

// ================= fused prep: ln1 + 6 weight transposes + bias concat + pb reorg =================
// grid 17152: [0,8192) ln1 rows; [8192,15104) weight transpose tiles; [15104,17152) pbT tiles.
// wq_t and bq are pre-scaled by QSCALE; pb table stored as f32 in C-fragment order, x log2(e).
__global__ __launch_bounds__(256) void mega_prep(
    const float* __restrict__ x, const float* __restrict__ g1, const float* __restrict__ b1,
    short* __restrict__ n1,
    const float* __restrict__ wq, const float* __restrict__ wk, const float* __restrict__ wv,
    const float* __restrict__ wo, const float* __restrict__ wf1, const float* __restrict__ wf2,
    const float* __restrict__ bq, const float* __restrict__ bk, const float* __restrict__ bv,
    short* __restrict__ wqkv_t, short* __restrict__ wo_t,
    short* __restrict__ w1_t, short* __restrict__ w2_t, float* __restrict__ bqkv,
    const float* __restrict__ pb, float* __restrict__ pbT)
{
  __shared__ float shbuf[32*33];
  int bx = blockIdx.x;
  int t = threadIdx.x;
  if (bx < 8192){
    // ---- LayerNorm row
    int row = bx;
    const float* xr = x + (size_t)row*D;
    float v0=xr[t], v1=xr[t+256], v2=xr[t+512];
    float s=v0+v1+v2, ss=v0*v0+v1*v1+v2*v2;
    #pragma unroll
    for (int m=1;m<64;m<<=1){ s += __shfl_xor(s,m); ss += __shfl_xor(ss,m); }
    int w=t>>6, lane=t&63;
    if (!lane){ shbuf[w]=s; shbuf[4+w]=ss; }
    __syncthreads();
    s = shbuf[0]+shbuf[1]+shbuf[2]+shbuf[3];
    ss = shbuf[4]+shbuf[5]+shbuf[6]+shbuf[7];
    float mu = s*(1.f/768.f);
    float inv = rsqrtf(ss*(1.f/768.f) - mu*mu + 1e-5f);
    short* o = n1 + (size_t)row*D;
    o[t]     = f2b((v0-mu)*inv*g1[t]     + b1[t]);
    o[t+256] = f2b((v1-mu)*inv*g1[t+256] + b1[t+256]);
    o[t+512] = f2b((v2-mu)*inv*g1[t+512] + b1[t+512]);
  } else if (bx < 15104){
    // ---- weight transpose+convert (f32 [K][Nc] -> bf16 [Nc][K]); bias concat in i<3
    int i = bx - 8192;
    if (i < 3){
      int j = i*256 + t;
      bqkv[j] = bq[j]*QSCALE; bqkv[768+j] = bk[j]; bqkv[1536+j] = bv[j];
    }
    const float* in; short* out; int K, Nc, bk_, bn_;
    float sc = 1.f;
    if (i < 2304){
      int which = i/576, ii = i - which*576;
      bk_ = ii%24; bn_ = ii/24; K = 768; Nc = 768;
      if      (which==0){ in = wq; out = wqkv_t; sc = QSCALE; }
      else if (which==1){ in = wk; out = wqkv_t + 768*768; }
      else if (which==2){ in = wv; out = wqkv_t + 2*768*768; }
      else              { in = wo; out = wo_t; }
    } else if (i < 4608){
      int ii = i - 2304; bk_ = ii%24; bn_ = ii/24; K = 768; Nc = 3072; in = wf1; out = w1_t;
    } else {
      int ii = i - 4608; bk_ = ii%96; bn_ = ii/96; K = 3072; Nc = 768; in = wf2; out = w2_t;
    }
    float (*tile)[33] = (float(*)[33])shbuf;
    int tx = t & 31, ty = t >> 5;
    #pragma unroll
    for (int j=0;j<4;++j)
      tile[ty + j*8][tx] = in[(size_t)(bk_*32 + ty + j*8)*Nc + bn_*32 + tx];
    __syncthreads();
    #pragma unroll
    for (int j=0;j<4;++j)
      out[(size_t)(bn_*32 + ty + j*8)*K + bk_*32 + tx] = f2b(tile[tx][ty + j*8] * sc);
  } else {
    // ---- position bias -> f32 fragment-order table, pre-multiplied by log2(e)
    int i = bx - 15104;
    int qt = i & 63, kb = i >> 6;
    int l = t >> 2;
    int vbase = (t & 3) * 8;
    int q = qt*32 + (l & 31);
    int hi = l >> 5;
    const float L2E = 1.4426950408889634f;
    float o[8];
    #pragma unroll
    for (int j=0;j<8;++j){
      int v = vbase + j;
      int r = v & 15, tile_ = v >> 4;
      int k = kb*64 + tile_*32 + 8*(r>>2) + (r&3) + 4*hi;
      o[j] = pb[(size_t)q*NB + k] * L2E;
    }
    float* dst = &pbT[(((size_t)(qt*32 + kb))*64 + l)*32 + vbase];
    f32x4 a; a[0]=o[0]; a[1]=o[1]; a[2]=o[2]; a[3]=o[3];
    f32x4 b; b[0]=o[4]; b[1]=o[5]; b[2]=o[6]; b[3]=o[7];
    *(f32x4*)dst = a;
    *(f32x4*)(dst+4) = b;
  }
}

// ---- LayerNorm: f32 [rows][768] -> bf16 (standalone, for ln2)
__global__ __launch_bounds__(256) void ln_k(const float* __restrict__ X, const float* __restrict__ gg,
                                            const float* __restrict__ bb, short* __restrict__ out){
  int row = blockIdx.x, t = threadIdx.x;
  const float* x = X + (size_t)row*D;
  float v0=x[t], v1=x[t+256], v2=x[t+512];
  float s=v0+v1+v2, ss=v0*v0+v1*v1+v2*v2;
  #pragma unroll
  for (int m=1;m<64;m<<=1){ s += __shfl_xor(s,m); ss += __shfl_xor(ss,m); }
  __shared__ float red[8];
  int w=t>>6, lane=t&63;
  if (!lane){ red[w]=s; red[4+w]=ss; }
  __syncthreads();
  s = red[0]+red[1]+red[2]+red[3];
  ss = red[4]+red[5]+red[6]+red[7];
  float mu = s*(1.f/768.f);
  float inv = rsqrtf(ss*(1.f/768.f) - mu*mu + 1e-5f);
  short* o = out + (size_t)row*D;
  o[t]     = f2b((v0-mu)*inv*gg[t]     + bb[t]);
  o[t+256] = f2b((v1-mu)*inv*gg[t+256] + bb[t+256]);
  o[t+512] = f2b((v2-mu)*inv*gg[t+512] + bb[t+512]);
}

// ================= GEMM bodies (chunk-XOR swizzled staging/reads, R16) =================
template<int MODE>
__device__ __forceinline__ void gbt_body(char* AsB, char* BsB, int m0, int n0,
    const short* __restrict__ A, const short* __restrict__ Bt,
    const float* __restrict__ bias, void* __restrict__ Cout, int Nc, int K)
{
  int t = threadIdx.x;
  int lane = t & 63, w = t >> 6;
  int wm = w >> 1, wn = w & 1;
  int r = lane & 15, g = lane >> 4;
  int schunk = (t&3) ^ ((t>>3)&3);
  const short* aSrc = A  + (size_t)(m0 + (t>>2))*K + schunk*8;
  const short* bSrc = Bt + (size_t)(n0 + (t>>2))*K + schunk*8;
  size_t rowK64 = (size_t)64*K;
  int dstOff = w*1024;
  int xr = (r>>1) & 3;
  f32x4 acc[4][4] = {};
  int nst = K >> 5;
  auto stage = [&](int u, int buf){
    char* ab = AsB + buf*8192;
    char* bb = BsB + buf*8192;
    int kt = u*32;
    gload16(aSrc + kt,          ab + dstOff);
    gload16(aSrc + kt + rowK64, ab + 4096 + dstOff);
    gload16(bSrc + kt,          bb + dstOff);
    gload16(bSrc + kt + rowK64, bb + 4096 + dstOff);
  };
  stage(0,0); stage(1,1);
  int cur = 0;
  for (int it=0; it<nst; ++it){
    if (it < nst-1) asm volatile("s_waitcnt vmcnt(4)" ::: "memory");
    else            asm volatile("s_waitcnt vmcnt(0)" ::: "memory");
    __builtin_amdgcn_s_barrier();
    __builtin_amdgcn_sched_barrier(0);
    if (it+2 < nst){
      int sb = cur+2; if (sb>=3) sb-=3;
      stage(it+2, sb);
    }
    short8 af[4], bfr[4];
    #pragma unroll
    for (int i=0;i<4;++i){
      af[i]  = *(const short8*)(AsB + cur*8192 + (wm*64 + i*16 + r)*64 + (g ^ xr)*16);
      bfr[i] = *(const short8*)(BsB + cur*8192 + (wn*64 + i*16 + r)*64 + (g ^ xr)*16);
    }
    #pragma unroll
    for (int i=0;i<4;++i)
      #pragma unroll
      for (int j=0;j<4;++j)
        acc[i][j] = __builtin_amdgcn_mfma_f32_16x16x32_bf16(af[i], bfr[j], acc[i][j], 0,0,0);
    cur = cur+1; if (cur>=3) cur-=3;
  }
  #pragma unroll
  for (int i=0;i<4;++i){
    #pragma unroll
    for (int j=0;j<4;++j){
      int col = n0 + wn*64 + j*16 + r;
      float bv = bias[col];
      #pragma unroll
      for (int q=0;q<4;++q){
        int row = m0 + wm*64 + i*16 + g*4 + q;
        size_t idx = (size_t)row*Nc + col;
        float val = acc[i][j][q] + bv;
        if constexpr (MODE==0){
          ((short*)Cout)[idx] = f2b(val);
        } else if constexpr (MODE==2){
          float ge = 0.5f*val*(1.f + erff(val*0.70710678118654752f));
          ((short*)Cout)[idx] = f2b(ge);
        }
      }
    }
  }
}

template<int MODE>
__device__ __forceinline__ void g64_body(char* AsB, char* BsB, int m0, int n0,
    const short* __restrict__ A, const short* __restrict__ Bt,
    const float* __restrict__ bias, const float* __restrict__ resid,
    void* __restrict__ Cout, int Nc, int K)
{
  int t = threadIdx.x;
  int lane = t & 63, w = t >> 6;
  int r = lane & 15, g = lane >> 4;
  int schunk = (t&3) ^ ((t>>3)&3);
  const short* aSrc = A  + (size_t)(m0 + (t>>2))*K + schunk*8;
  const short* bSrc = Bt + (size_t)(n0 + (t>>2))*K + schunk*8;
  size_t rowK64 = (size_t)64*K;
  int dstOff = w*1024;
  int xr = (r>>1) & 3;
  f32x4 acc[4][2] = {};
  int nst = K >> 5;
  auto stage = [&](int u, int buf){
    char* ab = AsB + buf*4096;
    char* bb = BsB + buf*8192;
    int kt = u*32;
    gload16(aSrc + kt,          ab + dstOff);
    gload16(bSrc + kt,          bb + dstOff);
    gload16(bSrc + kt + rowK64, bb + 4096 + dstOff);
  };
  stage(0,0); stage(1,1);
  int cur = 0;
  for (int it=0; it<nst; ++it){
    if (it < nst-1) asm volatile("s_waitcnt vmcnt(3)" ::: "memory");
    else            asm volatile("s_waitcnt vmcnt(0)" ::: "memory");
    __builtin_amdgcn_s_barrier();
    __builtin_amdgcn_sched_barrier(0);
    if (it+2 < nst){
      int sb = cur+2; if (sb>=3) sb-=3;
      stage(it+2, sb);
    }
    short8 af[4], bfr[2];
    #pragma unroll
    for (int i=0;i<4;++i) af[i] = *(const short8*)(AsB + cur*4096 + (i*16 + r)*64 + (g ^ xr)*16);
    #pragma unroll
    for (int j=0;j<2;++j) bfr[j] = *(const short8*)(BsB + cur*8192 + (w*32 + j*16 + r)*64 + (g ^ xr)*16);
    #pragma unroll
    for (int i=0;i<4;++i)
      #pragma unroll
      for (int j=0;j<2;++j)
        acc[i][j] = __builtin_amdgcn_mfma_f32_16x16x32_bf16(af[i], bfr[j], acc[i][j], 0,0,0);
    cur = cur+1; if (cur>=3) cur-=3;
  }
  #pragma unroll
  for (int i=0;i<4;++i){
    #pragma unroll
    for (int j=0;j<2;++j){
      int col = n0 + w*32 + j*16 + r;
      #pragma unroll
      for (int q=0;q<4;++q){
        int row = m0 + i*16 + g*4 + q;
        if constexpr (MODE==1){
          size_t idx = (size_t)row*Nc + col;
          ((float*)Cout)[idx] = acc[i][j][q] + bias[col] + resid[idx];
        } else {  // MODE 5: row = d (h*96+hd), col = global token (b*2048+n)
          int hh = row / 96, hd = row - hh*96;
          int bb = col >> 11, nn = col & 2047;
          size_t idx = ((size_t)((bb*8 + hh)*96 + hd))*2048 + nn;
          ((short*)Cout)[idx] = f2b(acc[i][j][q] + bias[row]);
        }
      }
    }
  }
}

template<int MODE>
__global__ __launch_bounds__(256) void gemm_bt(
    const short* __restrict__ A, const short* __restrict__ Bt,
    const float* __restrict__ bias, const float* __restrict__ resid,
    void* __restrict__ Cout, int Nc, int K)
{
  __shared__ __align__(16) char smem[49152];
  gbt_body<MODE>(smem, smem+24576, blockIdx.x*128, blockIdx.y*128, A, Bt, bias, Cout, Nc, K);
}

template<int MODE>
__global__ __launch_bounds__(256) void gemm64(
    const short* __restrict__ A, const short* __restrict__ Bt,
    const float* __restrict__ bias, const float* __restrict__ resid,
    void* __restrict__ Cout, int Nc, int K)
{
  __shared__ __align__(16) char smem[36864];
  g64_body<MODE>(smem, smem+12288, blockIdx.x*64, blockIdx.y*128, A, Bt, bias, resid, Cout, Nc, K);
}

// ---- fused QKV projection + V-transpose GEMM (independent outputs, one launch)
__global__ __launch_bounds__(256) void qkv_fused(
    const short* __restrict__ n1, const short* __restrict__ wqkv_t, const float* __restrict__ bqkv,
    const short* __restrict__ wv_t, const float* __restrict__ bv,
    short* __restrict__ qkv, short* __restrict__ v_t)
{
  __shared__ __align__(16) char smem[49152];
  int bx = blockIdx.x;
  if (bx < 768){
    gbt_body<0>(smem, smem+24576, (bx&63)*128, (bx>>6)*128, n1, wqkv_t, bqkv, qkv, 1536, 768);
  } else {
    int i = bx - 768;
    g64_body<5>(smem, smem+12288, (i%12)*64, (i/12)*128, wv_t, n1, bv, nullptr, v_t, 0, 768);
  }
}

// ---- Flash attention v12: v9 + pb-as-C-in (Q pre-scaled; pb f32 table feeds first MFMA's C)
__global__ __launch_bounds__(512, 1) void attn_k(const short* __restrict__ qkv, const short* __restrict__ v_t,
                                                 const float* __restrict__ pbT, short* __restrict__ aout){
  int bx = blockIdx.x;
  int h = bx & 7, b = (bx>>3)&3, qb = bx>>5;
  int t = threadIdx.x, l = t & 63, w = t >> 6;
  int l31 = l & 31, hi = l >> 5, l7 = l & 7;
  __shared__ __align__(16) short Ks[2][64][128];  // padded rows, XOR-swizzled chunks
  __shared__ __align__(16) short Vs[2][96][64];   // [d][k], source-XOR swizzled, dbuf

  // Q fragments (pre-scaled by QSCALE in projection): lane holds Q[q=l31][d=ds*16+hi*8+j]
  int qRow = qb*256 + w*32 + l31;
  const short* qg = qkv + (size_t)(b*NB + qRow)*1536 + h*HD;
  short8 qa[6];
  #pragma unroll
  for (int ds=0; ds<6; ++ds)
    qa[ds] = *(const short8*)&qg[ds*16 + hi*8];

  f32x16 oacc[3] = {};
  float m_run = -3.0e38f, l_run = 0.f;

  // K staging geometry (768 chunks of 16B over 512 threads), reg-staged ds_write
  int r0 = t/12,        c0 = t%12;
  int s1 = 512 + t;
  int r1 = s1/12,       c1 = s1%12;
  int ldsK0 = r0*128 + (c0 ^ (r0&7))*8;
  int ldsK1 = r1*128 + (c1 ^ (r1&7))*8;
  const short* kgB = qkv + (size_t)(b*NB)*1536 + 768 + h*HD;
  bool wlow = (t < 256);
  // V staging geometry: dest wave-uniform (HW adds lane*16), source XOR-swizzled
  int vr0 = t>>3,  vc0 = t&7;
  int vr1 = (512+t)>>3, vc1 = (512+t)&7;
  const short* vgB = v_t + (size_t)((b*H+h)*HD)*NB;
  const short* vsrc0 = vgB + (size_t)vr0*NB + (vc0 ^ (vr0&7))*8;
  const short* vsrc1 = vgB + (size_t)vr1*NB + (vc1 ^ (vr1&7))*8;
  // pbT per-lane base (f32): qt = qb*8 + w
  const float* pbB = pbT + (((size_t)((qb*8 + w)*32))*64 + l)*32;

  // prologue: stage K(0) into Ks[0]; issue V(0) gload -> Vs[0]
  {
    short8 ka = *(const short8*)&kgB[(size_t)r0*1536 + c0*8];
    short* ks0 = &Ks[0][0][0];
    *(short8*)(ks0 + ldsK0) = ka;
    if (wlow){
      short8 kb = *(const short8*)&kgB[(size_t)r1*1536 + c1*8];
      *(short8*)(ks0 + ldsK1) = kb;
    }
    gload16(vsrc0, (char*)Vs + w*1024);
    if (wlow) gload16(vsrc1, (char*)Vs + 8192 + w*1024);
  }
  __syncthreads();

  for (int kt=0; kt<32; ++kt){
    int cur = kt & 1;
    int kbase = kt*64;
    // --- issue order: K(kt+1) regs (oldest) -> pb(kt) -> V(kt+1) gload (newest)
    int kb2 = (kt < 31) ? (kbase + 64) : kbase;
    short8 kra = *(const short8*)&kgB[(size_t)(kb2 + r0)*1536 + c0*8];
    short8 krb = {};
    if (wlow) krb = *(const short8*)&kgB[(size_t)(kb2 + r1)*1536 + c1*8];
    const float* pbk = pbB + (size_t)kt*2048;
    f32x4 pf[8];
    #pragma unroll
    for (int j=0;j<8;++j) pf[j] = *(const f32x4*)&pbk[j*4];
    if (kt < 31){
      char* vbd = (char*)Vs + (cur^1)*12288;
      gload16(vsrc0 + kbase + 64, vbd + w*1024);
      if (wlow) gload16(vsrc1 + kbase + 64, vbd + 8192 + w*1024);
    }

    // --- QK^T with C-in = pb fragment: sacc = K·Q + pb (already log2-scaled)
    f32x16 sacc[2];
    #pragma unroll
    for (int tt=0; tt<2; ++tt)
      #pragma unroll
      for (int r=0; r<16; ++r){
        int v = tt*16 + r;
        sacc[tt][r] = pf[v>>2][v&3];
      }
    __builtin_amdgcn_s_setprio(1);
    #pragma unroll
    for (int tt=0; tt<2; ++tt){
      #pragma unroll
      for (int ds=0; ds<6; ++ds){
        short8 kf = *(const short8*)&Ks[cur][tt*32 + l31][((ds*2 + hi) ^ l7)*8];
        sacc[tt] = __builtin_amdgcn_mfma_f32_32x32x16_bf16(kf, qa[ds], sacc[tt], 0,0,0);
      }
    }
    __builtin_amdgcn_s_setprio(0);

    // --- softmax (log2 domain); vals == sacc directly
    float pm = sacc[0][0];
    #pragma unroll
    for (int tt=0; tt<2; ++tt)
      #pragma unroll
      for (int r=0; r<16; ++r) pm = fmaxf(pm, sacc[tt][r]);
    pm = fmaxf(pm, __shfl_xor(pm, 32));
    // defer-max rescale
    if (__any(pm - m_run > 8.f)){
      float mn = fmaxf(m_run, pm);
      float f = fexp2(m_run - mn);
      l_run *= f; m_run = mn;
      int fi = __float_as_int(f);
      #pragma unroll
      for (int reg=0; reg<16; ++reg){
        int q = (reg&3) + 8*(reg>>2) + 4*hi;
        float fr = __int_as_float(__builtin_amdgcn_ds_bpermute(q<<2, fi));
        oacc[0][reg] *= fr; oacc[1][reg] *= fr; oacc[2][reg] *= fr;
      }
    }
    float p[2][16];
    float rs = 0.f;
    #pragma unroll
    for (int tt=0; tt<2; ++tt)
      #pragma unroll
      for (int r=0; r<16; ++r){
        p[tt][r] = fexp2(sacc[tt][r] - m_run);
        rs += p[tt][r];
      }
    rs += __shfl_xor(rs, 32);
    l_run += rs;

    // --- pack P -> PV A-fragments via shfl_xor(32)
    short8 pa[4];
    #pragma unroll
    for (int ks=0; ks<4; ++ks){
      int tt = ks>>1;
      int rb = (ks&1)*8;
      unsigned G0a = cvtpk(p[tt][rb+0], p[tt][rb+1]);
      unsigned G0b = cvtpk(p[tt][rb+2], p[tt][rb+3]);
      unsigned G1a = cvtpk(p[tt][rb+4], p[tt][rb+5]);
      unsigned G1b = cvtpk(p[tt][rb+6], p[tt][rb+7]);
      unsigned sG0a = (unsigned)__shfl_xor((int)G0a, 32);
      unsigned sG0b = (unsigned)__shfl_xor((int)G0b, 32);
      unsigned sG1a = (unsigned)__shfl_xor((int)G1a, 32);
      unsigned sG1b = (unsigned)__shfl_xor((int)G1b, 32);
      int4v wv;
      wv[0] = hi ? (int)sG1a : (int)G0a;
      wv[1] = hi ? (int)sG1b : (int)G0b;
      wv[2] = hi ? (int)G1a  : (int)sG0a;
      wv[3] = hi ? (int)G1b  : (int)sG0b;
      pa[ks] = __builtin_bit_cast(short8, wv);
    }

    // --- PV: O[q][d] += P·V  (Vs[cur] staged last iteration, already visible)
    __builtin_amdgcn_s_setprio(1);
    #pragma unroll
    for (int dt=0; dt<3; ++dt){
      #pragma unroll
      for (int ks=0; ks<4; ++ks){
        short8 vb = *(const short8*)&Vs[cur][dt*32 + l31][((ks*2 + hi) ^ l7)*8];
        oacc[dt] = __builtin_amdgcn_mfma_f32_32x32x16_bf16(pa[ks], vb, oacc[dt], 0,0,0);
      }
    }
    __builtin_amdgcn_s_setprio(0);

    // --- write K(kt+1) into other buffer; single barrier per kt
    if (kt < 31){
      short* ksn = &Ks[cur^1][0][0];
      *(short8*)(ksn + ldsK0) = kra;
      if (wlow) *(short8*)(ksn + ldsK1) = krb;
      __syncthreads();
    }
  }

  // --- epilogue: normalize rows (gather 1/l per output row) and store
  float inv_self = 1.f / l_run;
  int ii = __float_as_int(inv_self);
  #pragma unroll
  for (int reg=0; reg<16; ++reg){
    int q = (reg&3) + 8*(reg>>2) + 4*hi;
    float invq = __int_as_float(__builtin_amdgcn_ds_bpermute(q<<2, ii));
    int rowg = b*NB + qb*256 + w*32 + q;
    #pragma unroll
    for (int dt=0; dt<3; ++dt){
      int col = h*HD + dt*32 + l31;
      aout[(size_t)rowg*D + col] = f2b(oacc[dt][reg] * invq);
    }
  }
}

extern "C" void kernel_launch(void* const* d_in, const int* in_sizes, int n_in,
                              void* d_out, int out_size, void* d_ws, size_t ws_size,
                              hipStream_t stream){
  const float* x   = (const float*)d_in[0];
  const float* pb  = (const float*)d_in[1];
  const float* wq  = (const float*)d_in[2];
  const float* bq  = (const float*)d_in[3];
  const float* wk  = (const float*)d_in[4];
  const float* bk  = (const float*)d_in[5];
  const float* wv  = (const float*)d_in[6];
  const float* bv  = (const float*)d_in[7];
  const float* wo  = (const float*)d_in[8];
  const float* bo  = (const float*)d_in[9];
  const float* g1  = (const float*)d_in[10];
  const float* b1  = (const float*)d_in[11];
  const float* g2  = (const float*)d_in[12];
  const float* b2  = (const float*)d_in[13];
  const float* wf1 = (const float*)d_in[14];
  const float* bf1 = (const float*)d_in[15];
  const float* wf2 = (const float*)d_in[16];
  const float* bf2 = (const float*)d_in[17];
  float* out = (float*)d_out;

  char* p = (char*)d_ws;
  auto alloc = [&](size_t bytes){ char* q = p; p += (bytes + 255) & ~(size_t)255; return q; };
  short* wqkv_t = (short*)alloc((size_t)2304*768*2);   // wq_t(scaled) | wk_t | wv_t
  short* wo_t   = (short*)alloc((size_t)768*768*2);
  short* w1_t   = (short*)alloc((size_t)3072*768*2);
  short* w2_t   = (short*)alloc((size_t)768*3072*2);
  float* bqkv   = (float*)alloc(2304*4);
  float* pbT    = (float*)alloc((size_t)2048*2048*4);  // f32 C-fragment table
  float* x1     = (float*)alloc((size_t)8192*768*4);
  short* n2     = (short*)alloc((size_t)8192*768*2);
  short* n1     = (short*)alloc((size_t)8192*768*2);   // reused as attn_out
  short* qkv    = (short*)alloc((size_t)8192*1536*2);  // Q(scaled)|K
  short* v_t    = (short*)alloc((size_t)32*96*2048*2);
  short* hbuf   = n1;       // FF1 out aliases n1+qkv+v_t (all dead by then)
  short* attn_o = n1;
  short* wv_t   = wqkv_t + (size_t)2*768*768;

  mega_prep<<<17152,256,0,stream>>>(x, g1, b1, n1,
                                    wq, wk, wv, wo, wf1, wf2, bq, bk, bv,
                                    wqkv_t, wo_t, w1_t, w2_t, bqkv, pb, pbT);
  qkv_fused<<<1536,256,0,stream>>>(n1, wqkv_t, bqkv, wv_t, bv, qkv, v_t);
  attn_k<<<256,512,0,stream>>>(qkv, v_t, pbT, attn_o);
  gemm64<1><<<dim3(128,6),256,0,stream>>>(attn_o, wo_t, bo, x, x1, 768, 768);
  ln_k<<<8192,256,0,stream>>>(x1, g2, b2, n2);
  gemm_bt<2><<<dim3(64,24),256,0,stream>>>(n2, w1_t, bf1, nullptr, hbuf, 3072, 768);
  gemm64<1><<<dim3(128,6),256,0,stream>>>(hbuf, w2_t, bf2, x1, out, 768, 3072);
}

// Round 18
// 300.079 us; speedup vs baseline: 1.1505x; 1.1505x over previous
//
#include <hip/hip_runtime.h>
#include <hip/hip_bf16.h>

#define D 768
#define H 8
#define HD 96
#define MLP 3072
#define NB 2048
#define BATCH 4

typedef __attribute__((ext_vector_type(8))) short short8;
typedef __attribute__((ext_vector_type(4))) short short4v;
typedef __attribute__((ext_vector_type(4))) float f32x4;
typedef __attribute__((ext_vector_type(16))) float f32x16;
typedef __attribute__((ext_vector_type(4))) int int4v;

typedef const __attribute__((address_space(1))) unsigned int gu32;
typedef __attribute__((address_space(3))) unsigned int lu32;

__device__ inline void gload16(const void* g, void* l){
  __builtin_amdgcn_global_load_lds((gu32*)g, (lu32*)l, 16, 0, 0);
}

__device__ inline short f2b(float f){
  __hip_bfloat16 h = __float2bfloat16(f);
  return *reinterpret_cast<short*>(&h);
}
__device__ inline float b2f(short s){
  return __uint_as_float(((unsigned)(unsigned short)s) << 16);
}
__device__ inline float fexp2(float x){ return __builtin_amdgcn_exp2f(x); }

__device__ inline unsigned cvtpk(float lo, float hi){
  unsigned r;
  asm volatile("v_cvt_pk_bf16_f32 %0, %1, %2" : "=v"(r) : "v"(lo), "v"(hi));
  return r;
}

// ================= fused prep: ln1 + 6 weight transposes + bias concat + pb reorg =================
// grid 17152: [0,8192) ln1 rows; [8192,15104) weight transpose tiles; [15104,17152) pbT tiles.
__global__ __launch_bounds__(256) void mega_prep(
    const float* __restrict__ x, const float* __restrict__ g1, const float* __restrict__ b1,
    short* __restrict__ n1,
    const float* __restrict__ wq, const float* __restrict__ wk, const float* __restrict__ wv,
    const float* __restrict__ wo, const float* __restrict__ wf1, const float* __restrict__ wf2,
    const float* __restrict__ bq, const float* __restrict__ bk, const float* __restrict__ bv,
    short* __restrict__ wqkv_t, short* __restrict__ wo_t,
    short* __restrict__ w1_t, short* __restrict__ w2_t, float* __restrict__ bqkv,
    const float* __restrict__ pb, short* __restrict__ pbT)
{
  __shared__ float shbuf[32*33];
  int bx = blockIdx.x;
  int t = threadIdx.x;
  if (bx < 8192){
    // ---- LayerNorm row
    int row = bx;
    const float* xr = x + (size_t)row*D;
    float v0=xr[t], v1=xr[t+256], v2=xr[t+512];
    float s=v0+v1+v2, ss=v0*v0+v1*v1+v2*v2;
    #pragma unroll
    for (int m=1;m<64;m<<=1){ s += __shfl_xor(s,m); ss += __shfl_xor(ss,m); }
    int w=t>>6, lane=t&63;
    if (!lane){ shbuf[w]=s; shbuf[4+w]=ss; }
    __syncthreads();
    s = shbuf[0]+shbuf[1]+shbuf[2]+shbuf[3];
    ss = shbuf[4]+shbuf[5]+shbuf[6]+shbuf[7];
    float mu = s*(1.f/768.f);
    float inv = rsqrtf(ss*(1.f/768.f) - mu*mu + 1e-5f);
    short* o = n1 + (size_t)row*D;
    o[t]     = f2b((v0-mu)*inv*g1[t]     + b1[t]);
    o[t+256] = f2b((v1-mu)*inv*g1[t+256] + b1[t+256]);
    o[t+512] = f2b((v2-mu)*inv*g1[t+512] + b1[t+512]);
  } else if (bx < 15104){
    // ---- weight transpose+convert (f32 [K][Nc] -> bf16 [Nc][K]); bias concat in i<3
    int i = bx - 8192;
    if (i < 3){
      int j = i*256 + t;
      bqkv[j] = bq[j]; bqkv[768+j] = bk[j]; bqkv[1536+j] = bv[j];
    }
    const float* in; short* out; int K, Nc, bk_, bn_;
    if (i < 2304){
      int which = i/576, ii = i - which*576;
      bk_ = ii%24; bn_ = ii/24; K = 768; Nc = 768;
      if      (which==0){ in = wq; out = wqkv_t; }
      else if (which==1){ in = wk; out = wqkv_t + 768*768; }
      else if (which==2){ in = wv; out = wqkv_t + 2*768*768; }
      else              { in = wo; out = wo_t; }
    } else if (i < 4608){
      int ii = i - 2304; bk_ = ii%24; bn_ = ii/24; K = 768; Nc = 3072; in = wf1; out = w1_t;
    } else {
      int ii = i - 4608; bk_ = ii%96; bn_ = ii/96; K = 3072; Nc = 768; in = wf2; out = w2_t;
    }
    float (*tile)[33] = (float(*)[33])shbuf;
    int tx = t & 31, ty = t >> 5;
    #pragma unroll
    for (int j=0;j<4;++j)
      tile[ty + j*8][tx] = in[(size_t)(bk_*32 + ty + j*8)*Nc + bn_*32 + tx];
    __syncthreads();
    #pragma unroll
    for (int j=0;j<4;++j)
      out[(size_t)(bn_*32 + ty + j*8)*K + bk_*32 + tx] = f2b(tile[tx][ty + j*8]);
  } else {
    // ---- position bias -> bf16 fragment-order table, pre-multiplied by log2(e)
    int i = bx - 15104;
    int qt = i & 63, kb = i >> 6;
    int l = t >> 2;
    int vbase = (t & 3) * 8;
    int q = qt*32 + (l & 31);
    int hi = l >> 5;
    const float L2E = 1.4426950408889634f;
    short8 o;
    #pragma unroll
    for (int j=0;j<8;++j){
      int v = vbase + j;
      int r = v & 15, tile_ = v >> 4;
      int k = kb*64 + tile_*32 + 8*(r>>2) + (r&3) + 4*hi;
      o[j] = f2b(pb[(size_t)q*NB + k] * L2E);
    }
    *(short8*)&pbT[(((size_t)(qt*32 + kb))*64 + l)*32 + vbase] = o;
  }
}

// ---- LayerNorm: f32 [rows][768] -> bf16 (standalone, for ln2)
__global__ __launch_bounds__(256) void ln_k(const float* __restrict__ X, const float* __restrict__ gg,
                                            const float* __restrict__ bb, short* __restrict__ out){
  int row = blockIdx.x, t = threadIdx.x;
  const float* x = X + (size_t)row*D;
  float v0=x[t], v1=x[t+256], v2=x[t+512];
  float s=v0+v1+v2, ss=v0*v0+v1*v1+v2*v2;
  #pragma unroll
  for (int m=1;m<64;m<<=1){ s += __shfl_xor(s,m); ss += __shfl_xor(ss,m); }
  __shared__ float red[8];
  int w=t>>6, lane=t&63;
  if (!lane){ red[w]=s; red[4+w]=ss; }
  __syncthreads();
  s = red[0]+red[1]+red[2]+red[3];
  ss = red[4]+red[5]+red[6]+red[7];
  float mu = s*(1.f/768.f);
  float inv = rsqrtf(ss*(1.f/768.f) - mu*mu + 1e-5f);
  short* o = out + (size_t)row*D;
  o[t]     = f2b((v0-mu)*inv*gg[t]     + bb[t]);
  o[t+256] = f2b((v1-mu)*inv*gg[t+256] + bb[t+256]);
  o[t+512] = f2b((v2-mu)*inv*gg[t+512] + bb[t+512]);
}

// ================= GEMM bodies =================
// Bank-conflict fix (rule #21 both-sides): each 64B LDS row holds its four 16B chunks
// permuted by chunk^((row>>1)&3), applied on the GLOBAL source (staging) and on the
// fragment-read index.
// 128x128, 3-buffer 1-barrier pipeline. MODE 0: +bias->bf16 | MODE 2: +bias,erf-GELU->bf16
template<int MODE>
__device__ __forceinline__ void gbt_body(char* AsB, char* BsB, int m0, int n0,
    const short* __restrict__ A, const short* __restrict__ Bt,
    const float* __restrict__ bias, void* __restrict__ Cout, int Nc, int K)
{
  int t = threadIdx.x;
  int lane = t & 63, w = t >> 6;
  int wm = w >> 1, wn = w & 1;
  int r = lane & 15, g = lane >> 4;
  int schunk = (t&3) ^ ((t>>3)&3);          // source chunk, pre-swizzled per rule #21
  const short* aSrc = A  + (size_t)(m0 + (t>>2))*K + schunk*8;
  const short* bSrc = Bt + (size_t)(n0 + (t>>2))*K + schunk*8;
  size_t rowK64 = (size_t)64*K;
  int dstOff = w*1024;
  int xr = (r>>1) & 3;                      // read-side XOR (row>>1)&3 == (r>>1)&3
  f32x4 acc[4][4] = {};
  int nst = K >> 5;
  auto stage = [&](int u, int buf){
    char* ab = AsB + buf*8192;
    char* bb = BsB + buf*8192;
    int kt = u*32;
    gload16(aSrc + kt,          ab + dstOff);
    gload16(aSrc + kt + rowK64, ab + 4096 + dstOff);
    gload16(bSrc + kt,          bb + dstOff);
    gload16(bSrc + kt + rowK64, bb + 4096 + dstOff);
  };
  stage(0,0); stage(1,1);
  int cur = 0;
  for (int it=0; it<nst; ++it){
    if (it < nst-1) asm volatile("s_waitcnt vmcnt(4)" ::: "memory");
    else            asm volatile("s_waitcnt vmcnt(0)" ::: "memory");
    __builtin_amdgcn_s_barrier();
    __builtin_amdgcn_sched_barrier(0);
    if (it+2 < nst){
      int sb = cur+2; if (sb>=3) sb-=3;
      stage(it+2, sb);
    }
    short8 af[4], bfr[4];
    #pragma unroll
    for (int i=0;i<4;++i){
      af[i]  = *(const short8*)(AsB + cur*8192 + (wm*64 + i*16 + r)*64 + (g ^ xr)*16);
      bfr[i] = *(const short8*)(BsB + cur*8192 + (wn*64 + i*16 + r)*64 + (g ^ xr)*16);
    }
    #pragma unroll
    for (int i=0;i<4;++i)
      #pragma unroll
      for (int j=0;j<4;++j)
        acc[i][j] = __builtin_amdgcn_mfma_f32_16x16x32_bf16(af[i], bfr[j], acc[i][j], 0,0,0);
    cur = cur+1; if (cur>=3) cur-=3;
  }
  #pragma unroll
  for (int i=0;i<4;++i){
    #pragma unroll
    for (int j=0;j<4;++j){
      int col = n0 + wn*64 + j*16 + r;
      float bv = bias[col];
      #pragma unroll
      for (int q=0;q<4;++q){
        int row = m0 + wm*64 + i*16 + g*4 + q;
        size_t idx = (size_t)row*Nc + col;
        float val = acc[i][j][q] + bv;
        if constexpr (MODE==0){
          ((short*)Cout)[idx] = f2b(val);
        } else if constexpr (MODE==2){
          float ge = 0.5f*val*(1.f + erff(val*0.70710678118654752f));
          ((short*)Cout)[idx] = f2b(ge);
        }
      }
    }
  }
}

// 64x128 tile, 3-buffer 1-barrier. MODE 1: +bias[col]+resid->f32 | MODE 5: V-scatter +bias[row]->bf16
template<int MODE>
__device__ __forceinline__ void g64_body(char* AsB, char* BsB, int m0, int n0,
    const short* __restrict__ A, const short* __restrict__ Bt,
    const float* __restrict__ bias, const float* __restrict__ resid,
    void* __restrict__ Cout, int Nc, int K)
{
  int t = threadIdx.x;
  int lane = t & 63, w = t >> 6;
  int r = lane & 15, g = lane >> 4;
  int schunk = (t&3) ^ ((t>>3)&3);
  const short* aSrc = A  + (size_t)(m0 + (t>>2))*K + schunk*8;
  const short* bSrc = Bt + (size_t)(n0 + (t>>2))*K + schunk*8;
  size_t rowK64 = (size_t)64*K;
  int dstOff = w*1024;
  int xr = (r>>1) & 3;
  f32x4 acc[4][2] = {};
  int nst = K >> 5;
  auto stage = [&](int u, int buf){
    char* ab = AsB + buf*4096;
    char* bb = BsB + buf*8192;
    int kt = u*32;
    gload16(aSrc + kt,          ab + dstOff);
    gload16(bSrc + kt,          bb + dstOff);
    gload16(bSrc + kt + rowK64, bb + 4096 + dstOff);
  };
  stage(0,0); stage(1,1);
  int cur = 0;
  for (int it=0; it<nst; ++it){
    if (it < nst-1) asm volatile("s_waitcnt vmcnt(3)" ::: "memory");
    else            asm volatile("s_waitcnt vmcnt(0)" ::: "memory");
    __builtin_amdgcn_s_barrier();
    __builtin_amdgcn_sched_barrier(0);
    if (it+2 < nst){
      int sb = cur+2; if (sb>=3) sb-=3;
      stage(it+2, sb);
    }
    short8 af[4], bfr[2];
    #pragma unroll
    for (int i=0;i<4;++i) af[i] = *(const short8*)(AsB + cur*4096 + (i*16 + r)*64 + (g ^ xr)*16);
    #pragma unroll
    for (int j=0;j<2;++j) bfr[j] = *(const short8*)(BsB + cur*8192 + (w*32 + j*16 + r)*64 + (g ^ xr)*16);
    #pragma unroll
    for (int i=0;i<4;++i)
      #pragma unroll
      for (int j=0;j<2;++j)
        acc[i][j] = __builtin_amdgcn_mfma_f32_16x16x32_bf16(af[i], bfr[j], acc[i][j], 0,0,0);
    cur = cur+1; if (cur>=3) cur-=3;
  }
  #pragma unroll
  for (int i=0;i<4;++i){
    #pragma unroll
    for (int j=0;j<2;++j){
      int col = n0 + w*32 + j*16 + r;
      #pragma unroll
      for (int q=0;q<4;++q){
        int row = m0 + i*16 + g*4 + q;
        if constexpr (MODE==1){
          size_t idx = (size_t)row*Nc + col;
          ((float*)Cout)[idx] = acc[i][j][q] + bias[col] + resid[idx];
        } else {  // MODE 5: row = d (h*96+hd), col = global token (b*2048+n)
          int hh = row / 96, hd = row - hh*96;
          int bb = col >> 11, nn = col & 2047;
          size_t idx = ((size_t)((bb*8 + hh)*96 + hd))*2048 + nn;
          ((short*)Cout)[idx] = f2b(acc[i][j][q] + bias[row]);
        }
      }
    }
  }
}

template<int MODE>
__global__ __launch_bounds__(256) void gemm_bt(
    const short* __restrict__ A, const short* __restrict__ Bt,
    const float* __restrict__ bias, const float* __restrict__ resid,
    void* __restrict__ Cout, int Nc, int K)
{
  __shared__ __align__(16) char smem[49152];
  gbt_body<MODE>(smem, smem+24576, blockIdx.x*128, blockIdx.y*128, A, Bt, bias, Cout, Nc, K);
}

template<int MODE>
__global__ __launch_bounds__(256) void gemm64(
    const short* __restrict__ A, const short* __restrict__ Bt,
    const float* __restrict__ bias, const float* __restrict__ resid,
    void* __restrict__ Cout, int Nc, int K)
{
  __shared__ __align__(16) char smem[36864];
  g64_body<MODE>(smem, smem+12288, blockIdx.x*64, blockIdx.y*128, A, Bt, bias, resid, Cout, Nc, K);
}

// ---- fused QKV projection + V-transpose GEMM (independent outputs, one launch)
__global__ __launch_bounds__(256) void qkv_fused(
    const short* __restrict__ n1, const short* __restrict__ wqkv_t, const float* __restrict__ bqkv,
    const short* __restrict__ wv_t, const float* __restrict__ bv,
    short* __restrict__ qkv, short* __restrict__ v_t)
{
  __shared__ __align__(16) char smem[49152];
  int bx = blockIdx.x;
  if (bx < 768){
    gbt_body<0>(smem, smem+24576, (bx&63)*128, (bx>>6)*128, n1, wqkv_t, bqkv, qkv, 1536, 768);
  } else {
    int i = bx - 768;
    g64_body<5>(smem, smem+12288, (i%12)*64, (i/12)*128, wv_t, n1, bv, nullptr, v_t, 0, 768);
  }
}

// ---- Flash attention v9 (best): 8 waves x 32 q-rows; 32x32x16 MFMA; swapped QK^T;
//      in-register softmax; K reg-staged XOR-swizzled LDS dbuf; V gload-lds dbuf;
//      ONE barrier per kt.
__global__ __launch_bounds__(512, 1) void attn_k(const short* __restrict__ qkv, const short* __restrict__ v_t,
                                                 const short* __restrict__ pbT, short* __restrict__ aout){
  int bx = blockIdx.x;
  int h = bx & 7, b = (bx>>3)&3, qb = bx>>5;
  int t = threadIdx.x, l = t & 63, w = t >> 6;
  int l31 = l & 31, hi = l >> 5, l7 = l & 7;
  __shared__ __align__(16) short Ks[2][64][128];  // padded rows, XOR-swizzled chunks
  __shared__ __align__(16) short Vs[2][96][64];   // [d][k], source-XOR swizzled, dbuf
  const float SCALE2 = 0.10206207261596575f * 1.4426950408889634f;  // 1/sqrt(96)*log2e

  // Q fragments: B-operand of mfma(K,Q): lane holds Q[q=l31][d = ds*16 + hi*8 + j]
  int qRow = qb*256 + w*32 + l31;
  const short* qg = qkv + (size_t)(b*NB + qRow)*1536 + h*HD;
  short8 qa[6];
  #pragma unroll
  for (int ds=0; ds<6; ++ds)
    qa[ds] = *(const short8*)&qg[ds*16 + hi*8];

  f32x16 oacc[3] = {};
  float m_run = -3.0e38f, l_run = 0.f;

  // K staging geometry (768 chunks of 16B over 512 threads), reg-staged ds_write
  int r0 = t/12,        c0 = t%12;
  int s1 = 512 + t;
  int r1 = s1/12,       c1 = s1%12;
  int ldsK0 = r0*128 + (c0 ^ (r0&7))*8;
  int ldsK1 = r1*128 + (c1 ^ (r1&7))*8;
  const short* kgB = qkv + (size_t)(b*NB)*1536 + 768 + h*HD;
  bool wlow = (t < 256);
  // V staging geometry: dest wave-uniform (HW adds lane*16), source XOR-swizzled
  int vr0 = t>>3,  vc0 = t&7;
  int vr1 = (512+t)>>3, vc1 = (512+t)&7;
  const short* vgB = v_t + (size_t)((b*H+h)*HD)*NB;
  const short* vsrc0 = vgB + (size_t)vr0*NB + (vc0 ^ (vr0&7))*8;
  const short* vsrc1 = vgB + (size_t)vr1*NB + (vc1 ^ (vr1&7))*8;
  // pbT per-lane base: qt = qb*8 + w
  const short* pbB = pbT + (((size_t)((qb*8 + w)*32))*64 + l)*32;

  // prologue: stage K(0) into Ks[0]; issue V(0) gload -> Vs[0]
  {
    short8 ka = *(const short8*)&kgB[(size_t)r0*1536 + c0*8];
    short* ks0 = &Ks[0][0][0];
    *(short8*)(ks0 + ldsK0) = ka;
    if (wlow){
      short8 kb = *(const short8*)&kgB[(size_t)r1*1536 + c1*8];
      *(short8*)(ks0 + ldsK1) = kb;
    }
    gload16(vsrc0, (char*)Vs + w*1024);
    if (wlow) gload16(vsrc1, (char*)Vs + 8192 + w*1024);
  }
  __syncthreads();

  for (int kt=0; kt<32; ++kt){
    int cur = kt & 1;
    int kbase = kt*64;
    // --- issue order: K(kt+1) regs (oldest) -> pb(kt) -> V(kt+1) gload (newest)
    int kb2 = (kt < 31) ? (kbase + 64) : kbase;
    short8 kra = *(const short8*)&kgB[(size_t)(kb2 + r0)*1536 + c0*8];
    short8 krb = {};
    if (wlow) krb = *(const short8*)&kgB[(size_t)(kb2 + r1)*1536 + c1*8];
    const short* pbk = pbB + kt*2048;
    short8 pbr0 = *(const short8*)&pbk[0];
    short8 pbr1 = *(const short8*)&pbk[8];
    short8 pbr2 = *(const short8*)&pbk[16];
    short8 pbr3 = *(const short8*)&pbk[24];
    if (kt < 31){
      char* vbd = (char*)Vs + (cur^1)*12288;
      gload16(vsrc0 + kbase + 64, vbd + w*1024);
      if (wlow) gload16(vsrc1 + kbase + 64, vbd + 8192 + w*1024);
    }

    // --- QK^T: S[k][q], A = K-frag from swizzled LDS, B = qa
    f32x16 sacc[2] = {};
    __builtin_amdgcn_s_setprio(1);
    #pragma unroll
    for (int tt=0; tt<2; ++tt){
      #pragma unroll
      for (int ds=0; ds<6; ++ds){
        short8 kf = *(const short8*)&Ks[cur][tt*32 + l31][((ds*2 + hi) ^ l7)*8];
        sacc[tt] = __builtin_amdgcn_mfma_f32_32x32x16_bf16(kf, qa[ds], sacc[tt], 0,0,0);
      }
    }
    __builtin_amdgcn_s_setprio(0);

    // --- softmax (log2 domain); lane owns full row q = l31 (kv-half per hi)
    float vals[2][16];
    #pragma unroll
    for (int tt=0; tt<2; ++tt)
      #pragma unroll
      for (int r=0; r<16; ++r){
        int v = tt*16 + r;
        short pv = (v<8)?pbr0[v]:(v<16)?pbr1[v-8]:(v<24)?pbr2[v-16]:pbr3[v-24];
        vals[tt][r] = fmaf(sacc[tt][r], SCALE2, b2f(pv));
      }
    float pm = vals[0][0];
    #pragma unroll
    for (int tt=0; tt<2; ++tt)
      #pragma unroll
      for (int r=0; r<16; ++r) pm = fmaxf(pm, vals[tt][r]);
    pm = fmaxf(pm, __shfl_xor(pm, 32));
    // defer-max rescale
    if (__any(pm - m_run > 8.f)){
      float mn = fmaxf(m_run, pm);
      float f = fexp2(m_run - mn);
      l_run *= f; m_run = mn;
      int fi = __float_as_int(f);
      #pragma unroll
      for (int reg=0; reg<16; ++reg){
        int q = (reg&3) + 8*(reg>>2) + 4*hi;
        float fr = __int_as_float(__builtin_amdgcn_ds_bpermute(q<<2, fi));
        oacc[0][reg] *= fr; oacc[1][reg] *= fr; oacc[2][reg] *= fr;
      }
    }
    float p[2][16];
    float rs = 0.f;
    #pragma unroll
    for (int tt=0; tt<2; ++tt)
      #pragma unroll
      for (int r=0; r<16; ++r){
        p[tt][r] = fexp2(vals[tt][r] - m_run);
        rs += p[tt][r];
      }
    rs += __shfl_xor(rs, 32);
    l_run += rs;

    // --- pack P -> PV A-fragments via shfl_xor(32)
    short8 pa[4];
    #pragma unroll
    for (int ks=0; ks<4; ++ks){
      int tt = ks>>1;
      int rb = (ks&1)*8;
      unsigned G0a = cvtpk(p[tt][rb+0], p[tt][rb+1]);
      unsigned G0b = cvtpk(p[tt][rb+2], p[tt][rb+3]);
      unsigned G1a = cvtpk(p[tt][rb+4], p[tt][rb+5]);
      unsigned G1b = cvtpk(p[tt][rb+6], p[tt][rb+7]);
      unsigned sG0a = (unsigned)__shfl_xor((int)G0a, 32);
      unsigned sG0b = (unsigned)__shfl_xor((int)G0b, 32);
      unsigned sG1a = (unsigned)__shfl_xor((int)G1a, 32);
      unsigned sG1b = (unsigned)__shfl_xor((int)G1b, 32);
      int4v wv;
      wv[0] = hi ? (int)sG1a : (int)G0a;
      wv[1] = hi ? (int)sG1b : (int)G0b;
      wv[2] = hi ? (int)G1a  : (int)sG0a;
      wv[3] = hi ? (int)G1b  : (int)sG0b;
      pa[ks] = __builtin_bit_cast(short8, wv);
    }

    // --- PV: O[q][d] += P·V  (Vs[cur] staged last iteration, already visible)
    __builtin_amdgcn_s_setprio(1);
    #pragma unroll
    for (int dt=0; dt<3; ++dt){
      #pragma unroll
      for (int ks=0; ks<4; ++ks){
        short8 vb = *(const short8*)&Vs[cur][dt*32 + l31][((ks*2 + hi) ^ l7)*8];
        oacc[dt] = __builtin_amdgcn_mfma_f32_32x32x16_bf16(pa[ks], vb, oacc[dt], 0,0,0);
      }
    }
    __builtin_amdgcn_s_setprio(0);

    // --- write K(kt+1) into other buffer; single barrier: drains V(kt+1) gloads
    //     (full iteration in flight) + makes K(kt+1) visible; WAR-safe by dbuf.
    if (kt < 31){
      short* ksn = &Ks[cur^1][0][0];
      *(short8*)(ksn + ldsK0) = kra;
      if (wlow) *(short8*)(ksn + ldsK1) = krb;
      __syncthreads();
    }
  }

  // --- epilogue: normalize rows (gather 1/l per output row) and store
  float inv_self = 1.f / l_run;
  int ii = __float_as_int(inv_self);
  #pragma unroll
  for (int reg=0; reg<16; ++reg){
    int q = (reg&3) + 8*(reg>>2) + 4*hi;
    float invq = __int_as_float(__builtin_amdgcn_ds_bpermute(q<<2, ii));
    int rowg = b*NB + qb*256 + w*32 + q;
    #pragma unroll
    for (int dt=0; dt<3; ++dt){
      int col = h*HD + dt*32 + l31;
      aout[(size_t)rowg*D + col] = f2b(oacc[dt][reg] * invq);
    }
  }
}

extern "C" void kernel_launch(void* const* d_in, const int* in_sizes, int n_in,
                              void* d_out, int out_size, void* d_ws, size_t ws_size,
                              hipStream_t stream){
  const float* x   = (const float*)d_in[0];
  const float* pb  = (const float*)d_in[1];
  const float* wq  = (const float*)d_in[2];
  const float* bq  = (const float*)d_in[3];
  const float* wk  = (const float*)d_in[4];
  const float* bk  = (const float*)d_in[5];
  const float* wv  = (const float*)d_in[6];
  const float* bv  = (const float*)d_in[7];
  const float* wo  = (const float*)d_in[8];
  const float* bo  = (const float*)d_in[9];
  const float* g1  = (const float*)d_in[10];
  const float* b1  = (const float*)d_in[11];
  const float* g2  = (const float*)d_in[12];
  const float* b2  = (const float*)d_in[13];
  const float* wf1 = (const float*)d_in[14];
  const float* bf1 = (const float*)d_in[15];
  const float* wf2 = (const float*)d_in[16];
  const float* bf2 = (const float*)d_in[17];
  float* out = (float*)d_out;

  char* p = (char*)d_ws;
  auto alloc = [&](size_t bytes){ char* q = p; p += (bytes + 255) & ~(size_t)255; return q; };
  short* wqkv_t = (short*)alloc((size_t)2304*768*2);   // wq_t | wk_t | wv_t
  short* wo_t   = (short*)alloc((size_t)768*768*2);
  short* w1_t   = (short*)alloc((size_t)3072*768*2);
  short* w2_t   = (short*)alloc((size_t)768*3072*2);
  float* bqkv   = (float*)alloc(2304*4);
  short* pbT    = (short*)alloc((size_t)2048*2048*2);
  float* x1     = (float*)alloc((size_t)8192*768*4);
  short* n2     = (short*)alloc((size_t)8192*768*2);
  short* n1     = (short*)alloc((size_t)8192*768*2);   // reused as attn_out
  short* qkv    = (short*)alloc((size_t)8192*1536*2);  // QK only
  short* v_t    = (short*)alloc((size_t)32*96*2048*2);
  short* hbuf   = n1;       // FF1 out aliases n1+qkv+v_t (all dead by then)
  short* attn_o = n1;
  short* wv_t   = wqkv_t + (size_t)2*768*768;

  mega_prep<<<17152,256,0,stream>>>(x, g1, b1, n1,
                                    wq, wk, wv, wo, wf1, wf2, bq, bk, bv,
                                    wqkv_t, wo_t, w1_t, w2_t, bqkv, pb, pbT);
  qkv_fused<<<1536,256,0,stream>>>(n1, wqkv_t, bqkv, wv_t, bv, qkv, v_t);
  attn_k<<<256,512,0,stream>>>(qkv, v_t, pbT, attn_o);
  gemm64<1><<<dim3(128,6),256,0,stream>>>(attn_o, wo_t, bo, x, x1, 768, 768);
  ln_k<<<8192,256,0,stream>>>(x1, g2, b2, n2);
  gemm_bt<2><<<dim3(64,24),256,0,stream>>>(n2, w1_t, bf1, nullptr, hbuf, 3072, 768);
  gemm64<1><<<dim3(128,6),256,0,stream>>>(hbuf, w2_t, bf2, x1, out, 768, 3072);
}